// Round 1
// baseline (2718.009 us; speedup 1.0000x reference)
//
#include <hip/hip_runtime.h>

// Problem constants
#define T_STEPS 512
#define BATCH   256
#define DIN     128
#define DH      512
#define DOUT    128

typedef __attribute__((ext_vector_type(8))) short  short8;   // 8 bf16 (4 VGPRs)
typedef __attribute__((ext_vector_type(4))) float  floatx4;  // MFMA acc

__device__ __forceinline__ float bf2f(unsigned short u) {
    union { unsigned int i; float f; } v; v.i = ((unsigned int)u) << 16; return v.f;
}
__device__ __forceinline__ unsigned short f2bf(float f) {
    union { float f; unsigned int i; } v; v.f = f;
    unsigned int b = v.i;
    b += 0x7FFFu + ((b >> 16) & 1u);   // RNE (inputs are finite/sane; no NaN path needed)
    return (unsigned short)(b >> 16);
}

// ---------------------------------------------------------------------------
// Pack a row-major fp32 [K][N] matrix into bf16 B-fragment order:
//   Wp[ntile][kc][lane][8], lane = quad*16 + (n&15), element j = k&7,
//   where ntile=n/16, kc=k/32, quad=(k%32)/8.
// A wave then loads one fragment as 16 contiguous bytes per lane (coalesced).
// ---------------------------------------------------------------------------
__global__ void pack_b_kernel(const float* __restrict__ W,
                              unsigned short* __restrict__ Wp, int K, int N) {
    int idx = blockIdx.x * blockDim.x + threadIdx.x;
    if (idx >= K * N) return;
    int k = idx / N, n = idx % N;
    int nt = n >> 4, kc = k >> 5, quad = (k >> 3) & 3, j = k & 7;
    int lane = quad * 16 + (n & 15);
    int KC = K >> 5;
    Wp[((size_t)(nt * KC + kc) * 64 + lane) * 8 + j] = f2bf(W[idx]);
}

// ---------------------------------------------------------------------------
// xproj: xp[tb][n] = sum_k xs[tb][k] * W1x[k][n], stored bf16.
// Block = 16 rows x 512 cols, 4 waves, wave w -> ntiles [8w, 8w+8).
// ---------------------------------------------------------------------------
__global__ __launch_bounds__(256) void xproj_kernel(
        const float* __restrict__ xs,
        const unsigned short* __restrict__ W1xp,
        unsigned short* __restrict__ xp) {
    const int tid  = threadIdx.x;
    const int lane = tid & 63;
    const int w    = tid >> 6;       // 0..3
    const int m    = lane & 15;
    const int q    = lane >> 4;
    const long row0 = (long)blockIdx.x * 16;

    // A-fragments: A[m][k], k = kc*32 + q*8 + j  (8 consecutive fp32 -> bf16)
    short8 a[4];
#pragma unroll
    for (int kc = 0; kc < 4; ++kc) {
        const float* src = xs + (row0 + m) * DIN + kc * 32 + q * 8;
        short8 av;
#pragma unroll
        for (int j = 0; j < 8; ++j) av[j] = (short)f2bf(src[j]);
        a[kc] = av;
    }

#pragma unroll
    for (int i = 0; i < 8; ++i) {
        const int nt = w * 8 + i;
        floatx4 acc = {0.f, 0.f, 0.f, 0.f};
#pragma unroll
        for (int kc = 0; kc < 4; ++kc) {
            short8 b = *(const short8*)(W1xp + ((size_t)(nt * 4 + kc) * 64 + lane) * 8);
            acc = __builtin_amdgcn_mfma_f32_16x16x32_bf16(a[kc], b, acc, 0, 0, 0);
        }
        // C/D: col = lane&15, row = q*4 + reg
#pragma unroll
        for (int r = 0; r < 4; ++r) {
            long row = row0 + q * 4 + r;
            xp[row * DH + nt * 16 + m] = f2bf(acc[r]);
        }
    }
}

// ---------------------------------------------------------------------------
// Recurrence + output tail. 16 blocks x 512 threads (8 waves).
// Block owns batch rows [16*blk, 16*blk+16). h double-buffered in LDS (bf16,
// row pad +8 -> conflict-free ds_read_b128). W1h streamed from L2 in packed
// bf16 fragment order. Wave w computes h columns [64w, 64w+64).
// ---------------------------------------------------------------------------
__global__ __launch_bounds__(512, 2) void rnn_kernel(
        const unsigned short* __restrict__ xp,
        const unsigned short* __restrict__ W1hp,
        const float* __restrict__ b1p,
        const float* __restrict__ W2,
        const float* __restrict__ b2p,
        float* __restrict__ out) {
    __shared__ unsigned short Hb[2][16][520];   // 520 = 512 + 8 pad (16B-aligned rows)

    const int tid  = threadIdx.x;
    const int lane = tid & 63;
    const int w    = tid >> 6;      // 0..7
    const int m    = lane & 15;
    const int q    = lane >> 4;
    const int row0 = blockIdx.x * 16;
    const float b1 = b1p[0];
    const int nt0  = w * 4;         // 4 n-tiles per wave

    for (int i = tid; i < 16 * 520; i += 512) ((unsigned short*)Hb[0])[i] = 0;
    __syncthreads();

    int p = 0;
#pragma unroll 1
    for (int t = 0; t < T_STEPS; ++t) {
        // Prefetch xp for the epilogue (HBM latency hidden under the MFMA loop)
        unsigned short xv[16];
#pragma unroll
        for (int i = 0; i < 4; ++i)
#pragma unroll
            for (int r = 0; r < 4; ++r)
                xv[i * 4 + r] =
                    xp[(size_t)(t * BATCH + row0 + q * 4 + r) * DH + (nt0 + i) * 16 + m];

        // A-fragments for all 16 k-chunks from LDS (ds_read_b128 each)
        short8 a[16];
#pragma unroll
        for (int kc = 0; kc < 16; ++kc)
            a[kc] = *(const short8*)&Hb[p][m][kc * 32 + q * 8];

        floatx4 acc[4];
#pragma unroll
        for (int i = 0; i < 4; ++i) acc[i] = (floatx4){0.f, 0.f, 0.f, 0.f};

        // k-outer / ntile-inner: 4 independent accumulator chains for ILP
#pragma unroll
        for (int kc = 0; kc < 16; ++kc) {
            const unsigned short* bp = W1hp + (size_t)kc * 512 + (size_t)lane * 8;
#pragma unroll
            for (int i = 0; i < 4; ++i) {
                short8 b = *(const short8*)(bp + (size_t)(nt0 + i) * 8192);
                acc[i] = __builtin_amdgcn_mfma_f32_16x16x32_bf16(a[kc], b, acc[i], 0, 0, 0);
            }
        }

        // Epilogue: h = tanh(acc + xp + b1) -> other LDS buffer
#pragma unroll
        for (int i = 0; i < 4; ++i)
#pragma unroll
            for (int r = 0; r < 4; ++r) {
                float v  = acc[i][r] + bf2f(xv[i * 4 + r]) + b1;
                float ex = __expf(v + v);
                float th = 1.f - 2.f / (ex + 1.f);
                Hb[1 - p][q * 4 + r][(nt0 + i) * 16 + m] = f2bf(th);
            }
        __syncthreads();
        p ^= 1;
    }

    // Tail: y = h_final @ W2 + b2. Wave w -> output cols [16w, 16w+16).
    const float b2 = b2p[0];
    floatx4 acc = {0.f, 0.f, 0.f, 0.f};
#pragma unroll
    for (int kc = 0; kc < 16; ++kc) {
        short8 av = *(const short8*)&Hb[p][m][kc * 32 + q * 8];
        short8 bv;
#pragma unroll
        for (int j = 0; j < 8; ++j)
            bv[j] = (short)f2bf(W2[(size_t)(kc * 32 + q * 8 + j) * DOUT + w * 16 + m]);
        acc = __builtin_amdgcn_mfma_f32_16x16x32_bf16(av, bv, acc, 0, 0, 0);
    }
#pragma unroll
    for (int r = 0; r < 4; ++r)
        out[(size_t)(row0 + q * 4 + r) * DOUT + w * 16 + m] = acc[r] + b2;
}

// ---------------------------------------------------------------------------
extern "C" void kernel_launch(void* const* d_in, const int* in_sizes, int n_in,
                              void* d_out, int out_size, void* d_ws, size_t ws_size,
                              hipStream_t stream) {
    const float* xs  = (const float*)d_in[0];
    const float* W1x = (const float*)d_in[1];
    const float* W1h = (const float*)d_in[2];
    const float* b1  = (const float*)d_in[3];
    const float* W2  = (const float*)d_in[4];
    const float* b2  = (const float*)d_in[5];
    float* out = (float*)d_out;

    // Workspace: xp (bf16, 134.2 MB) | W1h packed (512 KB) | W1x packed (128 KB)
    unsigned short* xp   = (unsigned short*)d_ws;
    unsigned short* w1hp = xp + (size_t)T_STEPS * BATCH * DH;
    unsigned short* w1xp = w1hp + (size_t)DH * DH;

    pack_b_kernel<<<(DH * DH + 255) / 256, 256, 0, stream>>>(W1h, w1hp, DH, DH);
    pack_b_kernel<<<(DIN * DH + 255) / 256, 256, 0, stream>>>(W1x, w1xp, DIN, DH);
    xproj_kernel<<<(T_STEPS * BATCH) / 16, 256, 0, stream>>>(xs, w1xp, xp);
    rnn_kernel<<<BATCH / 16, 512, 0, stream>>>(xp, w1hp, b1, W2, b2, out);
}